// Round 10
// baseline (1860.037 us; speedup 1.0000x reference)
//
#include <hip/hip_runtime.h>
#include <math.h>

#define VOCAB 1000
#define EMB   128
#define HID   256
#define G4    1024   // 4*HID
#define BATCH 64
#define SEQT  1024
#define KVH   48     // reg h2 cols per k-half (12 chunks)
#define KLH   16     // LDS h2 cols per k-half (4 chunks)

typedef unsigned int u32;
typedef _Float16 f16;
typedef __attribute__((ext_vector_type(2))) _Float16 h2v;
union H2U { u32 u; h2v h; unsigned short s[2]; };

#if defined(__has_builtin)
# if __has_builtin(__builtin_amdgcn_fdot2)
#  define HAVE_FDOT2 1
# endif
# if __has_builtin(__builtin_amdgcn_permlane32_swap)
#  define HAVE_PLSWAP 1
# endif
#endif

__device__ __forceinline__ float fdot2_(u32 a, u32 b, float c) {
    H2U ua, ub; ua.u = a; ub.u = b;
#ifdef HAVE_FDOT2
    return __builtin_amdgcn_fdot2(ua.h, ub.h, c, false);   // v_dot2_f32_f16
#else
    return c + (float)ua.h.x * (float)ub.h.x + (float)ua.h.y * (float)ub.h.y;
#endif
}

// Direction-proof lane-pair sum across the lane<32 / lane>=32 split.
// v_permlane32_swap_b32 exchanges one 32-lane half of vdst with the other
// half of src (direction was misread in R9 -> absmax 0.41). With BOTH
// operands = a, the sum of the two results equals a[l] + a[l^32] in EVERY
// lane under either direction convention. VALU pipe (~4cy), no lgkmcnt --
// avoids R8's ~120cy/op ds_bpermute that __shfl_xor(,32) lowers to.
__device__ __forceinline__ float pswapsum_(float a) {
#ifdef HAVE_PLSWAP
    typedef int i32x2 __attribute__((ext_vector_type(2)));
    i32x2 r = __builtin_amdgcn_permlane32_swap(
        (int)__float_as_uint(a), (int)__float_as_uint(a), false, false);
    return __uint_as_float((u32)r.x) + __uint_as_float((u32)r.y);
#else
    float b = a, c = a;
    asm volatile("v_permlane32_swap_b32 %0, %1" : "+v"(b), "+v"(c));
    return b + c;
#endif
}

__device__ __forceinline__ float sigmoidf_(float x) {
    return 1.f / (1.f + __expf(-x));
}
__device__ __forceinline__ float tanhf_(float x) {
    return 1.f - 2.f / (__expf(2.f * x) + 1.f);
}

// ---------------------------------------------------------------------------
// Kernel 1: eproj[v][g] = emb[v] . W_ih[g] + b_ih[g] + b_hh[g]   (fp32, exact)
// ---------------------------------------------------------------------------
__global__ __launch_bounds__(1024) void eproj_kernel(
    const float* __restrict__ emb, const float* __restrict__ W_ih,
    const float* __restrict__ b_ih, const float* __restrict__ b_hh,
    float* __restrict__ eproj)
{
    const int v = blockIdx.x;
    const int g = threadIdx.x;
    __shared__ __align__(16) float x_sh[EMB];
    if (g < EMB / 4) {
        ((float4*)x_sh)[g] = ((const float4*)(emb + (size_t)v * EMB))[g];
    }
    __syncthreads();
    const float4* wrow = (const float4*)(W_ih + (size_t)g * EMB);
    float a0 = 0.f, a1 = 0.f, a2 = 0.f, a3 = 0.f;
#pragma unroll
    for (int e4 = 0; e4 < EMB / 4; e4++) {
        float4 wv = wrow[e4];
        float4 xv = ((const float4*)x_sh)[e4];
        a0 += wv.x * xv.x;
        a1 += wv.y * xv.y;
        a2 += wv.z * xv.z;
        a3 += wv.w * xv.w;
    }
    eproj[(size_t)v * G4 + g] = (a0 + a1) + (a2 + a3) + b_ih[g] + b_hh[g];
}

// ---------------------------------------------------------------------------
// Kernel 2: pack W_hh fp32 -> fp16 half2, k-half split layout (same as R7/R8).
// h2 col m (0..127): half j = m>>6, within-half col mm = m&63.
// mm <  48 -> wvq chunk j*12 + mm/4  (register part, 24 chunks, 384 KB)
// mm >= 48 -> wlq chunk j*4 + (mm-48)/4  (LDS part, 8 chunks, 128 KB)
// [chunk][row][4] keeps global loads and LDS b128 reads lane-consecutive.
// ---------------------------------------------------------------------------
__global__ __launch_bounds__(128) void pack_whh(
    const float* __restrict__ Whh, u32* __restrict__ wvq, u32* __restrict__ wlq)
{
    const int r = blockIdx.x;        // row 0..1023
    const int m = threadIdx.x;       // h2 col 0..127
    H2U u;
    u.h.x = (f16)Whh[(size_t)r * HID + 2 * m];
    u.h.y = (f16)Whh[(size_t)r * HID + 2 * m + 1];
    const int j  = m >> 6;           // k-half
    const int mm = m & 63;
    if (mm < KVH) {
        const int chunk = j * (KVH / 4) + (mm >> 2);
        wvq[(size_t)chunk * (G4 * 4) + r * 4 + (mm & 3)] = u.u;
    } else {
        const int t2 = mm - KVH;
        const int chunk = j * (KLH / 4) + (t2 >> 2);
        wlq[(size_t)chunk * (G4 * 4) + r * 4 + (t2 & 3)] = u.u;
    }
}

// ---------------------------------------------------------------------------
// Kernel 3: single-CU LSTM, intra-wave k-split with VALU-pipe exchange.
// Ladder evidence: R7 cross-wave split 1498us (gs4 LDS bounce + 2 barriers);
// R8 intra-wave + __shfl_xor 1733us (4 serial ds_bpermute ~480cy); R9
// permlane wrong-direction (absmax 0.41). R10: same intra-wave layout
// (wave w, lane l -> u = w*32+(l&31), j = l>>5; ONE barrier/step, no gs4),
// exchange via direction-proof pswapsum_ -- every lane gets the full gate
// sum a_j0+a_j1, so the epilogue runs un-diverged on all 64 lanes (j=1
// lanes track c/h redundantly in regs); only the 16-bit h-store is masked.
// Critical path: dots -> 4 VALU swaps+adds (~40cy) -> epilogue -> h write
// -> barrier -> h read -> dots. h-broadcast: 2 uniform addrs/wave-read
// (2-way = free, m136); tail reads conflict-free (R8 PMC: 0 conflicts).
// x is counted once (j=0 accumulator); fp add commutativity keeps numerics
// identical to R7 -> absmax 0.001953125.
// ---------------------------------------------------------------------------
__global__ __launch_bounds__(512, 2) void lstm_single_cu(
    const int* __restrict__ ids, const int* __restrict__ lens,
    const float* __restrict__ eproj,
    const u32* __restrict__ wvq, const u32* __restrict__ wlq,
    float* __restrict__ out)
{
    const int b   = blockIdx.x;
    const int tau = threadIdx.x;                 // 0..511
    const int w   = tau >> 6;                    // wave 0..7
    const int l   = tau & 63;                    // lane
    const int u   = w * 32 + (l & 31);           // unit 0..255
    const int j   = l >> 5;                      // k-half (lane bit 5)
    const int rI  = u;                           // gate rows of unit u
    const int rF  = 256 + u;
    const int rG  = 512 + u;
    const int rO  = 768 + u;

    __shared__ u32 wl_sh[2 * (KLH / 4) * G4 * 4];  // 8 chunks x 1024 x 16B
    __shared__ u32 h2_sh[2][HID / 2];              // h as half2, parity x2
    __shared__ int id_sh[SEQT];                    // id row (4 KB)

    const int* idr = ids + (size_t)b * SEQT;
    ((int2*)id_sh)[tau] = ((const int2*)idr)[tau];    // 512 x 8B
    if (tau < HID / 2) h2_sh[0][tau] = 0u;            // h(0) = 0

    // stage LDS weight tail (b128 both sides, coalesced): 16 iters, 128 KB
    {
        const uint4* src = (const uint4*)wlq;
        uint4*       dst = (uint4*)wl_sh;
#pragma unroll
        for (int t = 0; t < 2 * (KLH / 4) * G4 / 512; t++)
            dst[t * 512 + tau] = src[t * 512 + tau];
    }

    // persistent weights: 4 gates x 48 h2 = 192 regs (VGPR+AGPR unified)
    u32 wI[KVH], wF[KVH], wG[KVH], wO[KVH];
#pragma unroll
    for (int q = 0; q < KVH / 4; q++) {
        const int ch = j * (KVH / 4) + q;
        uint4 ti = ((const uint4*)wvq)[ch * G4 + rI];
        uint4 tf = ((const uint4*)wvq)[ch * G4 + rF];
        uint4 tg = ((const uint4*)wvq)[ch * G4 + rG];
        uint4 to = ((const uint4*)wvq)[ch * G4 + rO];
        wI[4 * q + 0] = ti.x; wI[4 * q + 1] = ti.y;
        wI[4 * q + 2] = ti.z; wI[4 * q + 3] = ti.w;
        wF[4 * q + 0] = tf.x; wF[4 * q + 1] = tf.y;
        wF[4 * q + 2] = tf.z; wF[4 * q + 3] = tf.w;
        wG[4 * q + 0] = tg.x; wG[4 * q + 1] = tg.y;
        wG[4 * q + 2] = tg.z; wG[4 * q + 3] = tg.w;
        wO[4 * q + 0] = to.x; wO[4 * q + 1] = to.y;
        wO[4 * q + 2] = to.z; wO[4 * q + 3] = to.w;
    }

    const int len = lens[b];                     // >= 1
    float c = 0.f, hf = 0.f;

    // x projections live in the j=0 accumulators only (counted once)
    float xI = 0.f, xF = 0.f, xG = 0.f, xO = 0.f;
    if (j == 0) {
        const float* e0 = eproj + (size_t)idr[0] * G4;
        xI = e0[rI]; xF = e0[rF]; xG = e0[rG]; xO = e0[rO];
    }

    __syncthreads();

    for (int t = 0; t < len; t++) {
        // prefetch next step's input projections (j=0 lanes)
        const int nt = (t + 1 < len) ? t + 1 : len - 1;
        const int nid = id_sh[nt];
        float nI = 0.f, nF = 0.f, nG = 0.f, nO = 0.f;
        if (j == 0) {
            const float* en = eproj + (size_t)nid * G4;
            nI = en[rI]; nF = en[rF]; nG = en[rG]; nO = en[rO];
        }

        const int p = t & 1;
        const uint4* hb4 = (const uint4*)h2_sh[p] + 16 * j;  // this k-half
        float aI = xI, aF = xF, aG = xG, aO = xO;

        // register cols (12 chunks x 16 dots); 4 chains x 64 deep total
#pragma unroll
        for (int q = 0; q < KVH / 4; q++) {
            uint4 h4 = hb4[q];
            aI = fdot2_(wI[4 * q + 0], h4.x, aI);
            aF = fdot2_(wF[4 * q + 0], h4.x, aF);
            aG = fdot2_(wG[4 * q + 0], h4.x, aG);
            aO = fdot2_(wO[4 * q + 0], h4.x, aO);
            aI = fdot2_(wI[4 * q + 1], h4.y, aI);
            aF = fdot2_(wF[4 * q + 1], h4.y, aF);
            aG = fdot2_(wG[4 * q + 1], h4.y, aG);
            aO = fdot2_(wO[4 * q + 1], h4.y, aO);
            aI = fdot2_(wI[4 * q + 2], h4.z, aI);
            aF = fdot2_(wF[4 * q + 2], h4.z, aF);
            aG = fdot2_(wG[4 * q + 2], h4.z, aG);
            aO = fdot2_(wO[4 * q + 2], h4.z, aO);
            aI = fdot2_(wI[4 * q + 3], h4.w, aI);
            aF = fdot2_(wF[4 * q + 3], h4.w, aF);
            aG = fdot2_(wG[4 * q + 3], h4.w, aG);
            aO = fdot2_(wO[4 * q + 3], h4.w, aO);
        }
        // LDS tail (4 chunks; conflict-free per R8 PMC)
#pragma unroll
        for (int q = 0; q < KLH / 4; q++) {
            uint4 h4 = hb4[KVH / 4 + q];
            const int ch = j * (KLH / 4) + q;
            uint4 tI = ((const uint4*)wl_sh)[ch * G4 + rI];
            uint4 tF = ((const uint4*)wl_sh)[ch * G4 + rF];
            uint4 tG = ((const uint4*)wl_sh)[ch * G4 + rG];
            uint4 tO = ((const uint4*)wl_sh)[ch * G4 + rO];
            aI = fdot2_(tI.x, h4.x, aI);
            aF = fdot2_(tF.x, h4.x, aF);
            aG = fdot2_(tG.x, h4.x, aG);
            aO = fdot2_(tO.x, h4.x, aO);
            aI = fdot2_(tI.y, h4.y, aI);
            aF = fdot2_(tF.y, h4.y, aF);
            aG = fdot2_(tG.y, h4.y, aG);
            aO = fdot2_(tO.y, h4.y, aO);
            aI = fdot2_(tI.z, h4.z, aI);
            aF = fdot2_(tF.z, h4.z, aF);
            aG = fdot2_(tG.z, h4.z, aG);
            aO = fdot2_(tO.z, h4.z, aO);
            aI = fdot2_(tI.w, h4.w, aI);
            aF = fdot2_(tF.w, h4.w, aF);
            aG = fdot2_(tG.w, h4.w, aG);
            aO = fdot2_(tO.w, h4.w, aO);
        }

        // direction-proof pair sums: every lane gets the FULL gate sum
        float sI = pswapsum_(aI);
        float sF = pswapsum_(aF);
        float sG = pswapsum_(aG);
        float sO = pswapsum_(aO);

        // un-diverged epilogue on all 64 lanes (j=1 tracks c/h redundantly)
        float ig = sigmoidf_(sI);
        float fg = sigmoidf_(sF);
        float gg = tanhf_(sG);
        float og = sigmoidf_(sO);
        c  = fg * c + ig * gg;
        hf = og * tanhf_(c);
        if (j == 0) {                // only the h-store is masked
            H2U hv; hv.h.x = (f16)hf; hv.h.y = (f16)0.f;
            ((unsigned short*)h2_sh[p ^ 1])[u] = hv.s[0];
        }
        xI = nI; xF = nF; xG = nG; xO = nO;
        __syncthreads();             // ONE barrier/step: h(t+1) published
    }

    if (j == 0) out[(size_t)b * HID + u] = hf;
}

// ---------------------------------------------------------------------------
// Fallback (ws too small): correct-but-slow single-block fp32 version.
// ---------------------------------------------------------------------------
__global__ __launch_bounds__(1024, 1) void lstm_fallback(
    const int* __restrict__ ids, const int* __restrict__ lens,
    const float* __restrict__ emb, const float* __restrict__ W_ih,
    const float* __restrict__ b_ih, const float* __restrict__ b_hh,
    const float* __restrict__ W_hh, float* __restrict__ out)
{
    const int b = blockIdx.x;
    const int t = threadIdx.x;

    __shared__ __align__(16) float h_sh[HID];
    __shared__ __align__(16) float c_sh[HID];
    __shared__ __align__(16) float gates[G4];
    __shared__ __align__(16) float x_sh[EMB];

    float wih[EMB];
    {
        const float4* wr = (const float4*)(W_ih + (size_t)t * EMB);
#pragma unroll
        for (int e4 = 0; e4 < EMB / 4; e4++) {
            float4 wv = wr[e4];
            wih[4 * e4 + 0] = wv.x;
            wih[4 * e4 + 1] = wv.y;
            wih[4 * e4 + 2] = wv.z;
            wih[4 * e4 + 3] = wv.w;
        }
    }
    float bias = b_ih[t] + b_hh[t];

    const int len = lens[b];
    const int* ids_row = ids + (size_t)b * SEQT;
    if (t < HID) { h_sh[t] = 0.f; c_sh[t] = 0.f; }
    __syncthreads();

    for (int step = 0; step < len; step++) {
        int id = ids_row[step];
        if (t < EMB / 4) {
            ((float4*)x_sh)[t] = ((const float4*)(emb + (size_t)id * EMB))[t];
        }
        __syncthreads();
        float a0 = bias, a1 = 0.f, a2 = 0.f, a3 = 0.f;
#pragma unroll
        for (int e4 = 0; e4 < EMB / 4; e4++) {
            float4 xv = ((const float4*)x_sh)[e4];
            a0 += wih[4 * e4 + 0] * xv.x;
            a1 += wih[4 * e4 + 1] * xv.y;
            a2 += wih[4 * e4 + 2] * xv.z;
            a3 += wih[4 * e4 + 3] * xv.w;
        }
        float acc = (a0 + a1) + (a2 + a3);

        const float* wrow = W_hh + (size_t)t * HID;
        a0 = acc; a1 = 0.f; a2 = 0.f; a3 = 0.f;
        for (int k4 = 0; k4 < HID / 4; k4++) {
            float4 hv = ((const float4*)h_sh)[k4];
            float4 wv = ((const float4*)wrow)[k4];
            a0 += wv.x * hv.x;
            a1 += wv.y * hv.y;
            a2 += wv.z * hv.z;
            a3 += wv.w * hv.w;
        }
        gates[t] = (a0 + a1) + (a2 + a3);
        __syncthreads();

        if (t < HID) {
            float ig = sigmoidf_(gates[t]);
            float fg = sigmoidf_(gates[HID + t]);
            float gg = tanhf_(gates[2 * HID + t]);
            float og = sigmoidf_(gates[3 * HID + t]);
            float cc = fg * c_sh[t] + ig * gg;
            c_sh[t] = cc;
            h_sh[t] = og * tanhf_(cc);
        }
        __syncthreads();
    }
    if (t < HID) out[(size_t)b * HID + t] = h_sh[t];
}

extern "C" void kernel_launch(void* const* d_in, const int* in_sizes, int n_in,
                              void* d_out, int out_size, void* d_ws, size_t ws_size,
                              hipStream_t stream) {
    const int*   ids  = (const int*)d_in[0];
    const int*   lens = (const int*)d_in[1];
    const float* emb  = (const float*)d_in[2];
    const float* Wih  = (const float*)d_in[3];
    const float* Whh  = (const float*)d_in[4];
    const float* bih  = (const float*)d_in[5];
    const float* bhh  = (const float*)d_in[6];
    float* out = (float*)d_out;

    // ws layout: eproj 4 MB | wvq 384 KB | wlq 128 KB
    const size_t ep_bytes = (size_t)VOCAB * G4 * sizeof(float);
    const size_t wv_off   = ep_bytes;
    const size_t wv_bytes = (size_t)2 * (KVH / 4) * G4 * 4 * sizeof(u32);
    const size_t wl_off   = wv_off + wv_bytes;
    const size_t wl_bytes = (size_t)2 * (KLH / 4) * G4 * 4 * sizeof(u32);

    if (ws_size >= wl_off + wl_bytes) {
        float* eproj = (float*)d_ws;
        u32*   wvp   = (u32*)((char*)d_ws + wv_off);
        u32*   wlp   = (u32*)((char*)d_ws + wl_off);
        eproj_kernel<<<VOCAB, 1024, 0, stream>>>(emb, Wih, bih, bhh, eproj);
        pack_whh<<<G4, 128, 0, stream>>>(Whh, wvp, wlp);
        lstm_single_cu<<<BATCH, 512, 0, stream>>>(ids, lens, eproj, wvp, wlp, out);
    } else {
        lstm_fallback<<<BATCH, 1024, 0, stream>>>(
            ids, lens, emb, Wih, bih, bhh, Whh, out);
    }
}

// Round 11
// 1567.798 us; speedup vs baseline: 1.1864x; 1.1864x over previous
//
#include <hip/hip_runtime.h>
#include <math.h>

#define VOCAB 1000
#define EMB   128
#define HID   256
#define G4    1024   // 4*HID
#define BATCH 64
#define SEQT  1024
#define KVH   48     // reg h2 cols per k-half (12 chunks)
#define KLH   16     // LDS h2 cols per k-half (4 chunks)

typedef unsigned int u32;
typedef _Float16 f16;
typedef __attribute__((ext_vector_type(2))) _Float16 h2v;
union H2U { u32 u; h2v h; unsigned short s[2]; };

#if defined(__has_builtin)
# if __has_builtin(__builtin_amdgcn_fdot2)
#  define HAVE_FDOT2 1
# endif
#endif
__device__ __forceinline__ float fdot2_(u32 a, u32 b, float c) {
    H2U ua, ub; ua.u = a; ub.u = b;
#ifdef HAVE_FDOT2
    return __builtin_amdgcn_fdot2(ua.h, ub.h, c, false);   // v_dot2_f32_f16
#else
    return c + (float)ua.h.x * (float)ub.h.x + (float)ua.h.y * (float)ub.h.y;
#endif
}

__device__ __forceinline__ float sigmoidf_(float x) {
    return 1.f / (1.f + __expf(-x));
}
__device__ __forceinline__ float tanhf_(float x) {
    return 1.f - 2.f / (__expf(2.f * x) + 1.f);
}

// ---------------------------------------------------------------------------
// Kernel 1: eproj[v][g] = emb[v] . W_ih[g] + b_ih[g] + b_hh[g]   (fp32, exact)
// Rewritten: 8 vocab rows per block, so each block streams its W_ih row set
// ONCE for 8 outputs (L2 W_ih traffic 512 MB -> 64 MB; the old 1000-block
// version re-read the full 512 KB W_ih per block). Per-output fp op order
// (a0..a3 4-way partials, e4 ascending, then +b_ih+b_hh) is byte-identical
// to the original -> identical numerics.
// ---------------------------------------------------------------------------
__global__ __launch_bounds__(1024) void eproj_kernel(
    const float* __restrict__ emb, const float* __restrict__ W_ih,
    const float* __restrict__ b_ih, const float* __restrict__ b_hh,
    float* __restrict__ eproj)
{
    const int v0 = blockIdx.x * 8;               // 125 blocks x 8 = 1000
    const int g  = threadIdx.x;                  // gate row 0..1023
    __shared__ __align__(16) float4 x_sh[8][EMB / 4];   // 8 emb rows, 4 KB
    if (g < 256) {
        const int r = g >> 5, cc = g & 31;
        x_sh[r][cc] = ((const float4*)(emb + (size_t)(v0 + r) * EMB))[cc];
    }
    __syncthreads();
    const float4* wrow = (const float4*)(W_ih + (size_t)g * EMB);
    float a0[8], a1[8], a2[8], a3[8];
#pragma unroll
    for (int r = 0; r < 8; r++) { a0[r] = a1[r] = a2[r] = a3[r] = 0.f; }
#pragma unroll 4
    for (int e4 = 0; e4 < EMB / 4; e4++) {
        float4 wv = wrow[e4];
#pragma unroll
        for (int r = 0; r < 8; r++) {
            float4 xv = x_sh[r][e4];
            a0[r] += wv.x * xv.x;
            a1[r] += wv.y * xv.y;
            a2[r] += wv.z * xv.z;
            a3[r] += wv.w * xv.w;
        }
    }
    const float bias = b_ih[g] + b_hh[g];
#pragma unroll
    for (int r = 0; r < 8; r++)
        eproj[(size_t)(v0 + r) * G4 + g] =
            (a0[r] + a1[r]) + (a2[r] + a3[r]) + bias;
}

// ---------------------------------------------------------------------------
// Kernel 2: pack W_hh fp32 -> fp16 half2, k-half split layout (same as R7).
// h2 col m (0..127): half j = m>>6, within-half col mm = m&63.
// mm <  48 -> wvq chunk j*12 + mm/4  (register part, 24 chunks, 384 KB)
// mm >= 48 -> wlq chunk j*4 + (mm-48)/4  (LDS part, 8 chunks, 128 KB)
// [chunk][row][4] keeps global loads and LDS b128 reads lane-consecutive.
// ---------------------------------------------------------------------------
__global__ __launch_bounds__(128) void pack_whh(
    const float* __restrict__ Whh, u32* __restrict__ wvq, u32* __restrict__ wlq)
{
    const int r = blockIdx.x;        // row 0..1023
    const int m = threadIdx.x;       // h2 col 0..127
    H2U u;
    u.h.x = (f16)Whh[(size_t)r * HID + 2 * m];
    u.h.y = (f16)Whh[(size_t)r * HID + 2 * m + 1];
    const int j  = m >> 6;           // k-half
    const int mm = m & 63;
    if (mm < KVH) {
        const int chunk = j * (KVH / 4) + (mm >> 2);
        wvq[(size_t)chunk * (G4 * 4) + r * 4 + (mm & 3)] = u.u;
    } else {
        const int t2 = mm - KVH;
        const int chunk = j * (KLH / 4) + (t2 >> 2);
        wlq[(size_t)chunk * (G4 * 4) + r * 4 + (t2 & 3)] = u.u;
    }
}

// one register chunk (16 dots) / one LDS-tail chunk (4 reads + 16 dots)
#define REG_CHUNK(q) do {                                                   \
    uint4 h4 = hb4[(q)];                                                    \
    aI = fdot2_(wI[4*(q)+0], h4.x, aI); aF = fdot2_(wF[4*(q)+0], h4.x, aF); \
    aG = fdot2_(wG[4*(q)+0], h4.x, aG); aO = fdot2_(wO[4*(q)+0], h4.x, aO); \
    aI = fdot2_(wI[4*(q)+1], h4.y, aI); aF = fdot2_(wF[4*(q)+1], h4.y, aF); \
    aG = fdot2_(wG[4*(q)+1], h4.y, aG); aO = fdot2_(wO[4*(q)+1], h4.y, aO); \
    aI = fdot2_(wI[4*(q)+2], h4.z, aI); aF = fdot2_(wF[4*(q)+2], h4.z, aF); \
    aG = fdot2_(wG[4*(q)+2], h4.z, aG); aO = fdot2_(wO[4*(q)+2], h4.z, aO); \
    aI = fdot2_(wI[4*(q)+3], h4.w, aI); aF = fdot2_(wF[4*(q)+3], h4.w, aF); \
    aG = fdot2_(wG[4*(q)+3], h4.w, aG); aO = fdot2_(wO[4*(q)+3], h4.w, aO); \
} while (0)

#define TAIL_CHUNK(q) do {                                                  \
    uint4 h4 = hb4[KVH / 4 + (q)];                                          \
    const int ch = j * (KLH / 4) + (q);                                     \
    uint4 tI = ((const uint4*)wl_sh)[ch * G4 + rI];                         \
    uint4 tF = ((const uint4*)wl_sh)[ch * G4 + rF];                         \
    uint4 tG = ((const uint4*)wl_sh)[ch * G4 + rG];                         \
    uint4 tO = ((const uint4*)wl_sh)[ch * G4 + rO];                         \
    aI = fdot2_(tI.x, h4.x, aI); aF = fdot2_(tF.x, h4.x, aF);               \
    aG = fdot2_(tG.x, h4.x, aG); aO = fdot2_(tO.x, h4.x, aO);               \
    aI = fdot2_(tI.y, h4.y, aI); aF = fdot2_(tF.y, h4.y, aF);               \
    aG = fdot2_(tG.y, h4.y, aG); aO = fdot2_(tO.y, h4.y, aO);               \
    aI = fdot2_(tI.z, h4.z, aI); aF = fdot2_(tF.z, h4.z, aF);               \
    aG = fdot2_(tG.z, h4.z, aG); aO = fdot2_(tO.z, h4.z, aO);               \
    aI = fdot2_(tI.w, h4.w, aI); aF = fdot2_(tF.w, h4.w, aF);               \
    aG = fdot2_(tG.w, h4.w, aG); aO = fdot2_(tO.w, h4.w, aO);               \
} while (0)

// ---------------------------------------------------------------------------
// Kernel 3: single-CU LSTM, cross-wave k-split (the proven R7 structure,
// 1498us) + WAVE-PHASE STAGGER. Evidence: R8/R10 (intra-wave split) both
// land ~1740 regardless of exchange mechanism -> the cost was the 2-address
// h-broadcasts + doubled epilogue, and R7's cross-wave shape is right.
// Remaining gap to the pipe-sum floor is overlap: both waves on a SIMD run
// identical code from the same barrier, so they contend for the same pipe
// in phase (both VALU-heavy, then both LDS-heavy). Stagger: j=1 waves run
// the LDS-heavy tail loop FIRST, then the reg loop; j=0 runs reg-first.
// Each SIMD has one j=0 + one j=1 wave -> complementary phases, LDS pipe
// busy under the partner's VALU phase and vice versa. Only j=1's partial
// accumulation ORDER changes (same 64 terms) -> absmax well within the
// 7.85e-3 threshold. All addresses/layout identical to R7.
// ---------------------------------------------------------------------------
__global__ __launch_bounds__(512, 2) void lstm_single_cu(
    const int* __restrict__ ids, const int* __restrict__ lens,
    const float* __restrict__ eproj,
    const u32* __restrict__ wvq, const u32* __restrict__ wlq,
    float* __restrict__ out)
{
    const int b   = blockIdx.x;
    const int tau = threadIdx.x;                 // 0..511
    const int u   = tau & (HID - 1);             // unit
    const int j   = tau >> 8;                    // k-half (wave-uniform)
    const int rI  = u;                           // gate rows of unit u
    const int rF  = 256 + u;
    const int rG  = 512 + u;
    const int rO  = 768 + u;

    __shared__ u32    wl_sh[2 * (KLH / 4) * G4 * 4];  // 8 chunks x 1024 x 16B
    __shared__ u32    h2_sh[2][HID / 2];              // h as half2, parity x2
    __shared__ float4 gs4[HID];                       // j=1 partials bounce
    __shared__ int    id_sh[SEQT];                    // id row (4 KB)

    const int* idr = ids + (size_t)b * SEQT;
    ((int2*)id_sh)[tau] = ((const int2*)idr)[tau];    // 512 x 8B
    if (tau < HID / 2) h2_sh[0][tau] = 0u;            // h(0) = 0

    // stage LDS weight tail (b128 both sides, coalesced): 16 iters, 128 KB
    {
        const uint4* src = (const uint4*)wlq;
        uint4*       dst = (uint4*)wl_sh;
#pragma unroll
        for (int t = 0; t < 2 * (KLH / 4) * G4 / 512; t++)
            dst[t * 512 + tau] = src[t * 512 + tau];
    }

    // persistent weights: 4 gates x 48 h2 = 192 regs (VGPR+AGPR unified)
    u32 wI[KVH], wF[KVH], wG[KVH], wO[KVH];
#pragma unroll
    for (int q = 0; q < KVH / 4; q++) {
        const int ch = j * (KVH / 4) + q;
        uint4 ti = ((const uint4*)wvq)[ch * G4 + rI];
        uint4 tf = ((const uint4*)wvq)[ch * G4 + rF];
        uint4 tg = ((const uint4*)wvq)[ch * G4 + rG];
        uint4 to = ((const uint4*)wvq)[ch * G4 + rO];
        wI[4 * q + 0] = ti.x; wI[4 * q + 1] = ti.y;
        wI[4 * q + 2] = ti.z; wI[4 * q + 3] = ti.w;
        wF[4 * q + 0] = tf.x; wF[4 * q + 1] = tf.y;
        wF[4 * q + 2] = tf.z; wF[4 * q + 3] = tf.w;
        wG[4 * q + 0] = tg.x; wG[4 * q + 1] = tg.y;
        wG[4 * q + 2] = tg.z; wG[4 * q + 3] = tg.w;
        wO[4 * q + 0] = to.x; wO[4 * q + 1] = to.y;
        wO[4 * q + 2] = to.z; wO[4 * q + 3] = to.w;
    }

    const int len = lens[b];                     // >= 1
    float c = 0.f, hf = 0.f;

    // x projections live in the j=0 accumulators only
    float xI = 0.f, xF = 0.f, xG = 0.f, xO = 0.f;
    if (j == 0) {
        const float* e0 = eproj + (size_t)idr[0] * G4;
        xI = e0[rI]; xF = e0[rF]; xG = e0[rG]; xO = e0[rO];
    }

    __syncthreads();

    for (int t = 0; t < len; t++) {
        // prefetch next step's input projections (j=0 only, wave-uniform)
        const int nt = (t + 1 < len) ? t + 1 : len - 1;
        const int nid = id_sh[nt];
        float nI = 0.f, nF = 0.f, nG = 0.f, nO = 0.f;
        if (j == 0) {
            const float* en = eproj + (size_t)nid * G4;
            nI = en[rI]; nF = en[rF]; nG = en[rG]; nO = en[rO];
        }

        const int p = t & 1;
        const uint4* hb4 = (const uint4*)h2_sh[p] + 16 * j;  // this k-half
        float aI = xI, aF = xF, aG = xG, aO = xO;

        if (j == 0) {
            // j=0: VALU-heavy reg loop first, LDS-heavy tail second
#pragma unroll
            for (int q = 0; q < KVH / 4; q++) REG_CHUNK(q);
#pragma unroll
            for (int q = 0; q < KLH / 4; q++) TAIL_CHUNK(q);
        } else {
            // j=1: staggered -- tail (LDS) first, reg (VALU) second
#pragma unroll
            for (int q = 0; q < KLH / 4; q++) TAIL_CHUNK(q);
#pragma unroll
            for (int q = 0; q < KVH / 4; q++) REG_CHUNK(q);
        }

        if (j == 1) {                // publish raw k-half-1 partials (b128)
            gs4[u] = make_float4(aI, aF, aG, aO);
        }
        __syncthreads();             // barrier A: partials visible

        if (j == 0) {                // combine + activate + state update
            float4 pp = gs4[u];
            float ig = sigmoidf_(aI + pp.x);
            float fg = sigmoidf_(aF + pp.y);
            float gg = tanhf_(aG + pp.z);
            float og = sigmoidf_(aO + pp.w);
            c  = fg * c + ig * gg;
            hf = og * tanhf_(c);
            H2U hv; hv.h.x = (f16)hf; hv.h.y = (f16)0.f;
            ((unsigned short*)h2_sh[p ^ 1])[u] = hv.s[0];
        }
        xI = nI; xF = nF; xG = nG; xO = nO;
        __syncthreads();             // barrier B: h(t+1) published
    }

    if (tau < HID) out[(size_t)b * HID + u] = hf;   // j=0 threads hold state
}

// ---------------------------------------------------------------------------
// Fallback (ws too small): correct-but-slow single-block fp32 version.
// ---------------------------------------------------------------------------
__global__ __launch_bounds__(1024, 1) void lstm_fallback(
    const int* __restrict__ ids, const int* __restrict__ lens,
    const float* __restrict__ emb, const float* __restrict__ W_ih,
    const float* __restrict__ b_ih, const float* __restrict__ b_hh,
    const float* __restrict__ W_hh, float* __restrict__ out)
{
    const int b = blockIdx.x;
    const int t = threadIdx.x;

    __shared__ __align__(16) float h_sh[HID];
    __shared__ __align__(16) float c_sh[HID];
    __shared__ __align__(16) float gates[G4];
    __shared__ __align__(16) float x_sh[EMB];

    float wih[EMB];
    {
        const float4* wr = (const float4*)(W_ih + (size_t)t * EMB);
#pragma unroll
        for (int e4 = 0; e4 < EMB / 4; e4++) {
            float4 wv = wr[e4];
            wih[4 * e4 + 0] = wv.x;
            wih[4 * e4 + 1] = wv.y;
            wih[4 * e4 + 2] = wv.z;
            wih[4 * e4 + 3] = wv.w;
        }
    }
    float bias = b_ih[t] + b_hh[t];

    const int len = lens[b];
    const int* ids_row = ids + (size_t)b * SEQT;
    if (t < HID) { h_sh[t] = 0.f; c_sh[t] = 0.f; }
    __syncthreads();

    for (int step = 0; step < len; step++) {
        int id = ids_row[step];
        if (t < EMB / 4) {
            ((float4*)x_sh)[t] = ((const float4*)(emb + (size_t)id * EMB))[t];
        }
        __syncthreads();
        float a0 = bias, a1 = 0.f, a2 = 0.f, a3 = 0.f;
#pragma unroll
        for (int e4 = 0; e4 < EMB / 4; e4++) {
            float4 xv = ((const float4*)x_sh)[e4];
            a0 += wih[4 * e4 + 0] * xv.x;
            a1 += wih[4 * e4 + 1] * xv.y;
            a2 += wih[4 * e4 + 2] * xv.z;
            a3 += wih[4 * e4 + 3] * xv.w;
        }
        float acc = (a0 + a1) + (a2 + a3);

        const float* wrow = W_hh + (size_t)t * HID;
        a0 = acc; a1 = 0.f; a2 = 0.f; a3 = 0.f;
        for (int k4 = 0; k4 < HID / 4; k4++) {
            float4 hv = ((const float4*)h_sh)[k4];
            float4 wv = ((const float4*)wrow)[k4];
            a0 += wv.x * hv.x;
            a1 += wv.y * hv.y;
            a2 += wv.z * hv.z;
            a3 += wv.w * hv.w;
        }
        gates[t] = (a0 + a1) + (a2 + a3);
        __syncthreads();

        if (t < HID) {
            float ig = sigmoidf_(gates[t]);
            float fg = sigmoidf_(gates[HID + t]);
            float gg = tanhf_(gates[2 * HID + t]);
            float og = sigmoidf_(gates[3 * HID + t]);
            float cc = fg * c_sh[t] + ig * gg;
            c_sh[t] = cc;
            h_sh[t] = og * tanhf_(cc);
        }
        __syncthreads();
    }
    if (t < HID) out[(size_t)b * HID + t] = h_sh[t];
}

extern "C" void kernel_launch(void* const* d_in, const int* in_sizes, int n_in,
                              void* d_out, int out_size, void* d_ws, size_t ws_size,
                              hipStream_t stream) {
    const int*   ids  = (const int*)d_in[0];
    const int*   lens = (const int*)d_in[1];
    const float* emb  = (const float*)d_in[2];
    const float* Wih  = (const float*)d_in[3];
    const float* Whh  = (const float*)d_in[4];
    const float* bih  = (const float*)d_in[5];
    const float* bhh  = (const float*)d_in[6];
    float* out = (float*)d_out;

    // ws layout: eproj 4 MB | wvq 384 KB | wlq 128 KB
    const size_t ep_bytes = (size_t)VOCAB * G4 * sizeof(float);
    const size_t wv_off   = ep_bytes;
    const size_t wv_bytes = (size_t)2 * (KVH / 4) * G4 * 4 * sizeof(u32);
    const size_t wl_off   = wv_off + wv_bytes;
    const size_t wl_bytes = (size_t)2 * (KLH / 4) * G4 * 4 * sizeof(u32);

    if (ws_size >= wl_off + wl_bytes) {
        float* eproj = (float*)d_ws;
        u32*   wvp   = (u32*)((char*)d_ws + wv_off);
        u32*   wlp   = (u32*)((char*)d_ws + wl_off);
        eproj_kernel<<<VOCAB / 8, 1024, 0, stream>>>(emb, Wih, bih, bhh, eproj);
        pack_whh<<<G4, 128, 0, stream>>>(Whh, wvp, wlp);
        lstm_single_cu<<<BATCH, 512, 0, stream>>>(ids, lens, eproj, wvp, wlp, out);
    } else {
        lstm_fallback<<<BATCH, 1024, 0, stream>>>(
            ids, lens, emb, Wih, bih, bhh, Whh, out);
    }
}

// Round 12
// 1562.072 us; speedup vs baseline: 1.1907x; 1.0037x over previous
//
#include <hip/hip_runtime.h>
#include <math.h>

#define VOCAB 1000
#define EMB   128
#define HID   256
#define G4    1024   // 4*HID
#define BATCH 64
#define SEQT  1024
#define KVH   48     // reg h2 cols per k-half (12 chunks, cols 0-47)
#define KLS   8      // LDS h2 cols per k-half (2 chunks, cols 48-55)
#define KGH   8      // L2-global h2 cols per k-half (2 chunks, cols 56-63)

typedef unsigned int u32;
typedef _Float16 f16;
typedef __attribute__((ext_vector_type(2))) _Float16 h2v;
union H2U { u32 u; h2v h; unsigned short s[2]; };

#if defined(__has_builtin)
# if __has_builtin(__builtin_amdgcn_fdot2)
#  define HAVE_FDOT2 1
# endif
#endif
__device__ __forceinline__ float fdot2_(u32 a, u32 b, float c) {
    H2U ua, ub; ua.u = a; ub.u = b;
#ifdef HAVE_FDOT2
    return __builtin_amdgcn_fdot2(ua.h, ub.h, c, false);   // v_dot2_f32_f16
#else
    return c + (float)ua.h.x * (float)ub.h.x + (float)ua.h.y * (float)ub.h.y;
#endif
}

__device__ __forceinline__ float sigmoidf_(float x) {
    return 1.f / (1.f + __expf(-x));
}
__device__ __forceinline__ float tanhf_(float x) {
    return 1.f - 2.f / (__expf(2.f * x) + 1.f);
}

// ---------------------------------------------------------------------------
// Kernel 1: eproj[v][g] = emb[v] . W_ih[g] + b_ih[g] + b_hh[g]   (fp32, exact)
// 8 vocab rows per block: W_ih streamed once per 8 outputs (R11's proven
// version, L2 W_ih traffic 512 MB -> 64 MB). Per-output fp op order
// byte-identical to the original.
// ---------------------------------------------------------------------------
__global__ __launch_bounds__(1024) void eproj_kernel(
    const float* __restrict__ emb, const float* __restrict__ W_ih,
    const float* __restrict__ b_ih, const float* __restrict__ b_hh,
    float* __restrict__ eproj)
{
    const int v0 = blockIdx.x * 8;               // 125 blocks x 8 = 1000
    const int g  = threadIdx.x;                  // gate row 0..1023
    __shared__ __align__(16) float4 x_sh[8][EMB / 4];   // 8 emb rows, 4 KB
    if (g < 256) {
        const int r = g >> 5, cc = g & 31;
        x_sh[r][cc] = ((const float4*)(emb + (size_t)(v0 + r) * EMB))[cc];
    }
    __syncthreads();
    const float4* wrow = (const float4*)(W_ih + (size_t)g * EMB);
    float a0[8], a1[8], a2[8], a3[8];
#pragma unroll
    for (int r = 0; r < 8; r++) { a0[r] = a1[r] = a2[r] = a3[r] = 0.f; }
#pragma unroll 4
    for (int e4 = 0; e4 < EMB / 4; e4++) {
        float4 wv = wrow[e4];
#pragma unroll
        for (int r = 0; r < 8; r++) {
            float4 xv = x_sh[r][e4];
            a0[r] += wv.x * xv.x;
            a1[r] += wv.y * xv.y;
            a2[r] += wv.z * xv.z;
            a3[r] += wv.w * xv.w;
        }
    }
    const float bias = b_ih[g] + b_hh[g];
#pragma unroll
    for (int r = 0; r < 8; r++)
        eproj[(size_t)(v0 + r) * G4 + g] =
            (a0[r] + a1[r]) + (a2[r] + a3[r]) + bias;
}

// ---------------------------------------------------------------------------
// Kernel 2: pack W_hh fp32 -> fp16 half2, 3-way k-half split layout.
// h2 col m (0..127): half j = m>>6, within-half col mm = m&63.
// mm <  48       -> wvq chunk j*12 + mm/4        (register part, 24 ch, 384 KB)
// 48 <= mm < 56  -> wlq chunk j*2 + (mm-48)/4    (LDS part, 4 ch, 64 KB)
// mm >= 56       -> wgq chunk j*2 + (mm-56)/4    (L2-global part, 4 ch, 64 KB)
// [chunk][row][4] keeps global loads and LDS b128 reads lane-consecutive.
// ---------------------------------------------------------------------------
__global__ __launch_bounds__(128) void pack_whh(
    const float* __restrict__ Whh, u32* __restrict__ wvq,
    u32* __restrict__ wlq, u32* __restrict__ wgq)
{
    const int r = blockIdx.x;        // row 0..1023
    const int m = threadIdx.x;       // h2 col 0..127
    H2U u;
    u.h.x = (f16)Whh[(size_t)r * HID + 2 * m];
    u.h.y = (f16)Whh[(size_t)r * HID + 2 * m + 1];
    const int j  = m >> 6;           // k-half
    const int mm = m & 63;
    if (mm < KVH) {
        const int chunk = j * (KVH / 4) + (mm >> 2);
        wvq[(size_t)chunk * (G4 * 4) + r * 4 + (mm & 3)] = u.u;
    } else if (mm < KVH + KLS) {
        const int t2 = mm - KVH;
        const int chunk = j * (KLS / 4) + (t2 >> 2);
        wlq[(size_t)chunk * (G4 * 4) + r * 4 + (t2 & 3)] = u.u;
    } else {
        const int t2 = mm - KVH - KLS;
        const int chunk = j * (KGH / 4) + (t2 >> 2);
        wgq[(size_t)chunk * (G4 * 4) + r * 4 + (t2 & 3)] = u.u;
    }
}

// one register chunk (16 dots)
#define REG_CHUNK(q) do {                                                   \
    uint4 h4 = hb4[(q)];                                                    \
    aI = fdot2_(wI[4*(q)+0], h4.x, aI); aF = fdot2_(wF[4*(q)+0], h4.x, aF); \
    aG = fdot2_(wG[4*(q)+0], h4.x, aG); aO = fdot2_(wO[4*(q)+0], h4.x, aO); \
    aI = fdot2_(wI[4*(q)+1], h4.y, aI); aF = fdot2_(wF[4*(q)+1], h4.y, aF); \
    aG = fdot2_(wG[4*(q)+1], h4.y, aG); aO = fdot2_(wO[4*(q)+1], h4.y, aO); \
    aI = fdot2_(wI[4*(q)+2], h4.z, aI); aF = fdot2_(wF[4*(q)+2], h4.z, aF); \
    aG = fdot2_(wG[4*(q)+2], h4.z, aG); aO = fdot2_(wO[4*(q)+2], h4.z, aO); \
    aI = fdot2_(wI[4*(q)+3], h4.w, aI); aF = fdot2_(wF[4*(q)+3], h4.w, aF); \
    aG = fdot2_(wG[4*(q)+3], h4.w, aG); aO = fdot2_(wO[4*(q)+3], h4.w, aO); \
} while (0)

// one in-register (pre-loaded) chunk: weights tI..tO vs h chunk hq
#define VAL_CHUNK(tI, tF, tG, tO, hq) do {                                  \
    uint4 h4 = hb4[(hq)];                                                   \
    aI = fdot2_((tI).x, h4.x, aI); aF = fdot2_((tF).x, h4.x, aF);           \
    aG = fdot2_((tG).x, h4.x, aG); aO = fdot2_((tO).x, h4.x, aO);           \
    aI = fdot2_((tI).y, h4.y, aI); aF = fdot2_((tF).y, h4.y, aF);           \
    aG = fdot2_((tG).y, h4.y, aG); aO = fdot2_((tO).y, h4.y, aO);           \
    aI = fdot2_((tI).z, h4.z, aI); aF = fdot2_((tF).z, h4.z, aF);           \
    aG = fdot2_((tG).z, h4.z, aG); aO = fdot2_((tO).z, h4.z, aO);           \
    aI = fdot2_((tI).w, h4.w, aI); aF = fdot2_((tF).w, h4.w, aF);           \
    aG = fdot2_((tG).w, h4.w, aG); aO = fdot2_((tO).w, h4.w, aO);           \
} while (0)

// ---------------------------------------------------------------------------
// Kernel 3: single-CU LSTM, cross-wave k-split (R7/R11 structure) with the
// weight tail REBALANCED across pipes. R11 counters: step ~3500cy, LDS pipe
// ~2050cy (tail 128 lane-spread b128 ~1540 + h-broadcast ~510) is the
// heaviest pipe; VALU ~1150; VMEM idle. Move half the tail (cols 56-63 of
// each k-half, 64KB total, L2-resident and shared by the 8 blocks/XCD) to
// global loads, CROSS-STEP pipelined: the 8 dwordx4 loads are issued AFTER
// this step's dots (loop-invariant addresses) and consumed at the TOP of
// the next step -- the in-flight window spans only exchange+barriers+
// epilogue (~400-600cy >> 200cy L2 latency), where dot temps are dead, so
// peak live regs stay under the 256 unified cap (R1's global-tail attempt
// died precisely because its in-flight buffers spanned the dot region).
// LDS tail per CU: 128 -> 64 wave-reads (-770cy on the critical pipe);
// VMEM gains 64 wave-loads on an idle pipe. Stagger dropped (R11: null).
// Per-gate accumulation order becomes x + global(56-63) + reg(0-47) +
// LDS(48-55): same terms, benign fp reorder (threshold 7.85e-3, we run
// ~2e-3). Tripwire: WRITE_SIZE >> 64KB = spill -> retreat to 1 global chunk.
// ---------------------------------------------------------------------------
__global__ __launch_bounds__(512, 2) void lstm_single_cu(
    const int* __restrict__ ids, const int* __restrict__ lens,
    const float* __restrict__ eproj,
    const u32* __restrict__ wvq, const u32* __restrict__ wlq,
    const u32* __restrict__ wgq, float* __restrict__ out)
{
    const int b   = blockIdx.x;
    const int tau = threadIdx.x;                 // 0..511
    const int u   = tau & (HID - 1);             // unit
    const int j   = tau >> 8;                    // k-half (wave-uniform)
    const int rI  = u;                           // gate rows of unit u
    const int rF  = 256 + u;
    const int rG  = 512 + u;
    const int rO  = 768 + u;

    __shared__ u32    wl_sh[4 * G4 * 4];         // 4 chunks x 1024 x 16B = 64KB
    __shared__ u32    h2_sh[2][HID / 2];         // h as half2, parity x2
    __shared__ float4 gs4[HID];                  // j=1 partials bounce
    __shared__ int    id_sh[SEQT];               // id row (4 KB)

    const int* idr = ids + (size_t)b * SEQT;
    ((int2*)id_sh)[tau] = ((const int2*)idr)[tau];    // 512 x 8B
    if (tau < HID / 2) h2_sh[0][tau] = 0u;            // h(0) = 0

    // stage LDS weight tail (b128 both sides, coalesced): 8 iters, 64 KB
    {
        const uint4* src = (const uint4*)wlq;
        uint4*       dst = (uint4*)wl_sh;
#pragma unroll
        for (int t = 0; t < 4 * G4 / 512; t++)
            dst[t * 512 + tau] = src[t * 512 + tau];
    }

    // persistent weights: 4 gates x 48 h2 = 192 regs (VGPR+AGPR unified)
    u32 wI[KVH], wF[KVH], wG[KVH], wO[KVH];
#pragma unroll
    for (int q = 0; q < KVH / 4; q++) {
        const int ch = j * (KVH / 4) + q;
        uint4 ti = ((const uint4*)wvq)[ch * G4 + rI];
        uint4 tf = ((const uint4*)wvq)[ch * G4 + rF];
        uint4 tg = ((const uint4*)wvq)[ch * G4 + rG];
        uint4 to = ((const uint4*)wvq)[ch * G4 + rO];
        wI[4 * q + 0] = ti.x; wI[4 * q + 1] = ti.y;
        wI[4 * q + 2] = ti.z; wI[4 * q + 3] = ti.w;
        wF[4 * q + 0] = tf.x; wF[4 * q + 1] = tf.y;
        wF[4 * q + 2] = tf.z; wF[4 * q + 3] = tf.w;
        wG[4 * q + 0] = tg.x; wG[4 * q + 1] = tg.y;
        wG[4 * q + 2] = tg.z; wG[4 * q + 3] = tg.w;
        wO[4 * q + 0] = to.x; wO[4 * q + 1] = to.y;
        wO[4 * q + 2] = to.z; wO[4 * q + 3] = to.w;
    }

    // loop-invariant global-tail bases (2 chunks for this thread's k-half)
    const uint4* g0 = (const uint4*)wgq + (size_t)(2 * j + 0) * G4;
    const uint4* g1 = (const uint4*)wgq + (size_t)(2 * j + 1) * G4;

    const int len = lens[b];                     // >= 1
    float c = 0.f, hf = 0.f;

    // x projections live in the j=0 accumulators only
    float xI = 0.f, xF = 0.f, xG = 0.f, xO = 0.f;
    if (j == 0) {
        const float* e0 = eproj + (size_t)idr[0] * G4;
        xI = e0[rI]; xF = e0[rF]; xG = e0[rG]; xO = e0[rO];
    }

    // prologue: issue the first global-tail loads (consumed at step-0 top)
    uint4 gi0 = g0[rI], gf0 = g0[rF], gg0 = g0[rG], go0 = g0[rO];
    uint4 gi1 = g1[rI], gf1 = g1[rF], gg1 = g1[rG], go1 = g1[rO];

    __syncthreads();

    for (int t = 0; t < len; t++) {
        // prefetch next step's input projections (j=0 only, wave-uniform)
        const int nt = (t + 1 < len) ? t + 1 : len - 1;
        const int nid = id_sh[nt];
        float nI = 0.f, nF = 0.f, nG = 0.f, nO = 0.f;
        if (j == 0) {
            const float* en = eproj + (size_t)nid * G4;
            nI = en[rI]; nF = en[rF]; nG = en[rG]; nO = en[rO];
        }

        const int p = t & 1;
        const uint4* hb4 = (const uint4*)h2_sh[p] + 16 * j;  // this k-half
        float aI = xI, aF = xF, aG = xG, aO = xO;

        // global tail (cols 56-63): consume the in-flight loads first,
        // so the buffers are dead before the reg-dot region begins
        VAL_CHUNK(gi0, gf0, gg0, go0, 14);
        VAL_CHUNK(gi1, gf1, gg1, go1, 15);

        // register cols 0..47 (12 chunks)
#pragma unroll
        for (int q = 0; q < KVH / 4; q++) REG_CHUNK(q);

        // LDS tail (cols 48-55, 2 chunks; lane-consecutive b128)
#pragma unroll
        for (int q = 0; q < KLS / 4; q++) {
            const int ch = j * (KLS / 4) + q;
            uint4 tI = ((const uint4*)wl_sh)[ch * G4 + rI];
            uint4 tF = ((const uint4*)wl_sh)[ch * G4 + rF];
            uint4 tG = ((const uint4*)wl_sh)[ch * G4 + rG];
            uint4 tO = ((const uint4*)wl_sh)[ch * G4 + rO];
            VAL_CHUNK(tI, tF, tG, tO, KVH / 4 + q);
        }

        // issue next step's global-tail loads: loop-invariant addresses,
        // L2-hot (64KB shared per XCD). In-flight across the epilogue
        // window only (~400-600cy of cover vs ~200cy L2 latency).
        gi0 = g0[rI]; gf0 = g0[rF]; gg0 = g0[rG]; go0 = g0[rO];
        gi1 = g1[rI]; gf1 = g1[rF]; gg1 = g1[rG]; go1 = g1[rO];

        if (j == 1) {                // publish raw k-half-1 partials (b128)
            gs4[u] = make_float4(aI, aF, aG, aO);
        }
        __syncthreads();             // barrier A: partials visible

        if (j == 0) {                // combine + activate + state update
            float4 pp = gs4[u];
            float ig = sigmoidf_(aI + pp.x);
            float fg = sigmoidf_(aF + pp.y);
            float gg2 = tanhf_(aG + pp.z);
            float og = sigmoidf_(aO + pp.w);
            c  = fg * c + ig * gg2;
            hf = og * tanhf_(c);
            H2U hv; hv.h.x = (f16)hf; hv.h.y = (f16)0.f;
            ((unsigned short*)h2_sh[p ^ 1])[u] = hv.s[0];
        }
        xI = nI; xF = nF; xG = nG; xO = nO;
        __syncthreads();             // barrier B: h(t+1) published
    }

    if (tau < HID) out[(size_t)b * HID + u] = hf;   // j=0 threads hold state
}

// ---------------------------------------------------------------------------
// Fallback (ws too small): correct-but-slow single-block fp32 version.
// ---------------------------------------------------------------------------
__global__ __launch_bounds__(1024, 1) void lstm_fallback(
    const int* __restrict__ ids, const int* __restrict__ lens,
    const float* __restrict__ emb, const float* __restrict__ W_ih,
    const float* __restrict__ b_ih, const float* __restrict__ b_hh,
    const float* __restrict__ W_hh, float* __restrict__ out)
{
    const int b = blockIdx.x;
    const int t = threadIdx.x;

    __shared__ __align__(16) float h_sh[HID];
    __shared__ __align__(16) float c_sh[HID];
    __shared__ __align__(16) float gates[G4];
    __shared__ __align__(16) float x_sh[EMB];

    float wih[EMB];
    {
        const float4* wr = (const float4*)(W_ih + (size_t)t * EMB);
#pragma unroll
        for (int e4 = 0; e4 < EMB / 4; e4++) {
            float4 wv = wr[e4];
            wih[4 * e4 + 0] = wv.x;
            wih[4 * e4 + 1] = wv.y;
            wih[4 * e4 + 2] = wv.z;
            wih[4 * e4 + 3] = wv.w;
        }
    }
    float bias = b_ih[t] + b_hh[t];

    const int len = lens[b];
    const int* ids_row = ids + (size_t)b * SEQT;
    if (t < HID) { h_sh[t] = 0.f; c_sh[t] = 0.f; }
    __syncthreads();

    for (int step = 0; step < len; step++) {
        int id = ids_row[step];
        if (t < EMB / 4) {
            ((float4*)x_sh)[t] = ((const float4*)(emb + (size_t)id * EMB))[t];
        }
        __syncthreads();
        float a0 = bias, a1 = 0.f, a2 = 0.f, a3 = 0.f;
#pragma unroll
        for (int e4 = 0; e4 < EMB / 4; e4++) {
            float4 xv = ((const float4*)x_sh)[e4];
            a0 += wih[4 * e4 + 0] * xv.x;
            a1 += wih[4 * e4 + 1] * xv.y;
            a2 += wih[4 * e4 + 2] * xv.z;
            a3 += wih[4 * e4 + 3] * xv.w;
        }
        float acc = (a0 + a1) + (a2 + a3);

        const float* wrow = W_hh + (size_t)t * HID;
        a0 = acc; a1 = 0.f; a2 = 0.f; a3 = 0.f;
        for (int k4 = 0; k4 < HID / 4; k4++) {
            float4 hv = ((const float4*)h_sh)[k4];
            float4 wv = ((const float4*)wrow)[k4];
            a0 += wv.x * hv.x;
            a1 += wv.y * hv.y;
            a2 += wv.z * hv.z;
            a3 += wv.w * hv.w;
        }
        gates[t] = (a0 + a1) + (a2 + a3);
        __syncthreads();

        if (t < HID) {
            float ig = sigmoidf_(gates[t]);
            float fg = sigmoidf_(gates[HID + t]);
            float gg = tanhf_(gates[2 * HID + t]);
            float og = sigmoidf_(gates[3 * HID + t]);
            float cc = fg * c_sh[t] + ig * gg;
            c_sh[t] = cc;
            h_sh[t] = og * tanhf_(cc);
        }
        __syncthreads();
    }
    if (t < HID) out[(size_t)b * HID + t] = h_sh[t];
}

extern "C" void kernel_launch(void* const* d_in, const int* in_sizes, int n_in,
                              void* d_out, int out_size, void* d_ws, size_t ws_size,
                              hipStream_t stream) {
    const int*   ids  = (const int*)d_in[0];
    const int*   lens = (const int*)d_in[1];
    const float* emb  = (const float*)d_in[2];
    const float* Wih  = (const float*)d_in[3];
    const float* Whh  = (const float*)d_in[4];
    const float* bih  = (const float*)d_in[5];
    const float* bhh  = (const float*)d_in[6];
    float* out = (float*)d_out;

    // ws layout: eproj 4 MB | wvq 384 KB | wlq 64 KB | wgq 64 KB
    const size_t ep_bytes = (size_t)VOCAB * G4 * sizeof(float);
    const size_t wv_off   = ep_bytes;
    const size_t wv_bytes = (size_t)2 * (KVH / 4) * G4 * 4 * sizeof(u32);
    const size_t wl_off   = wv_off + wv_bytes;
    const size_t wl_bytes = (size_t)2 * (KLS / 4) * G4 * 4 * sizeof(u32);
    const size_t wg_off   = wl_off + wl_bytes;
    const size_t wg_bytes = (size_t)2 * (KGH / 4) * G4 * 4 * sizeof(u32);

    if (ws_size >= wg_off + wg_bytes) {
        float* eproj = (float*)d_ws;
        u32*   wvp   = (u32*)((char*)d_ws + wv_off);
        u32*   wlp   = (u32*)((char*)d_ws + wl_off);
        u32*   wgp   = (u32*)((char*)d_ws + wg_off);
        eproj_kernel<<<VOCAB / 8, 1024, 0, stream>>>(emb, Wih, bih, bhh, eproj);
        pack_whh<<<G4, 128, 0, stream>>>(Whh, wvp, wlp, wgp);
        lstm_single_cu<<<BATCH, 512, 0, stream>>>(
            ids, lens, eproj, wvp, wlp, wgp, out);
    } else {
        lstm_fallback<<<BATCH, 1024, 0, stream>>>(
            ids, lens, emb, Wih, bih, bhh, Whh, out);
    }
}